// Round 1
// baseline (597.946 us; speedup 1.0000x reference)
//
#include <hip/hip_runtime.h>

// TopK-and-scatter: out[r,c] = x[r,c] if x[r,c] is among the top-64 of row r
// (ties at the threshold broken by LOWEST column index, matching lax.top_k),
// else 0. Exact, bit-exact selection via 3-round radix select on
// order-preserving uint32 keys, row resident in registers.

#define TPB   1024
#define COLS  32768
#define EPT   32          // elements per thread = COLS / TPB
#define KSEL  64u
#define NB1   4096        // round-1 bins (key bits [31:20])

__device__ __forceinline__ void suffixScanFind(
    unsigned int* hist, int nb, int tid,
    unsigned int need, int* sBin, unsigned int* sAbove)
{
    // In-place suffix (from-the-right inclusive) scan, then find the unique
    // bin B with  suffix(B) >= need > suffix(B+1).
    if (nb == 4096) {
        for (int stride = 1; stride < 4096; stride <<= 1) {
            unsigned int t[4];
            #pragma unroll
            for (int c = 0; c < 4; ++c) {
                const int i = tid + c * 1024;
                const unsigned int a = hist[i];
                const unsigned int b = (i + stride < 4096) ? hist[i + stride] : 0u;
                t[c] = a + b;
            }
            __syncthreads();
            #pragma unroll
            for (int c = 0; c < 4; ++c) hist[tid + c * 1024] = t[c];
            __syncthreads();
        }
        #pragma unroll
        for (int c = 0; c < 4; ++c) {
            const int i = tid + c * 1024;
            const unsigned int s0 = hist[i];
            const unsigned int s1 = (i + 1 < 4096) ? hist[i + 1] : 0u;
            if (s0 >= need && s1 < need) { *sBin = i; *sAbove = s1; }
        }
        __syncthreads();
    } else { // nb == 1024, one bin per thread
        for (int stride = 1; stride < 1024; stride <<= 1) {
            const unsigned int a = hist[tid];
            const unsigned int b = (tid + stride < 1024) ? hist[tid + stride] : 0u;
            const unsigned int t = a + b;
            __syncthreads();
            hist[tid] = t;
            __syncthreads();
        }
        const unsigned int s0 = hist[tid];
        const unsigned int s1 = (tid + 1 < 1024) ? hist[tid + 1] : 0u;
        if (s0 >= need && s1 < need) { *sBin = tid; *sAbove = s1; }
        __syncthreads();
    }
}

__global__ __launch_bounds__(TPB) void topk_scatter_kernel(
    const float* __restrict__ x, float* __restrict__ out)
{
    __shared__ unsigned int hist[NB1];
    __shared__ int          sBin;
    __shared__ unsigned int sAbove;
    __shared__ unsigned int eqN;
    __shared__ int          eqIdx[256];

    const int tid = threadIdx.x;
    const long long row = blockIdx.x;
    const float4* __restrict__ xrow = (const float4*)(x + row * (long long)COLS);
    float4* __restrict__ orow       = (float4*)(out + row * (long long)COLS);

    // ---- load row into registers as order-preserving keys ----
    unsigned int key[EPT];
    #pragma unroll
    for (int j = 0; j < 8; ++j) {
        const float4 v = xrow[j * TPB + tid];
        #pragma unroll
        for (int l = 0; l < 4; ++l) {
            const unsigned int b = __float_as_uint((&v.x)[l]);
            key[j * 4 + l] = b ^ ((unsigned int)((int)b >> 31) | 0x80000000u);
        }
    }

    unsigned int need = KSEL;

    // ---- Round 1: bits [31:20], 4096 bins ----
    #pragma unroll
    for (int c = 0; c < 4; ++c) hist[tid + c * 1024] = 0u;
    __syncthreads();
    #pragma unroll
    for (int e = 0; e < EPT; ++e) atomicAdd(&hist[key[e] >> 20], 1u);
    __syncthreads();
    suffixScanFind(hist, 4096, tid, need, &sBin, &sAbove);
    const unsigned int b1 = (unsigned int)sBin;
    need -= sAbove;

    // ---- Round 2: bits [19:10] among prefix-matching, 1024 bins ----
    hist[tid] = 0u;
    __syncthreads();
    #pragma unroll
    for (int e = 0; e < EPT; ++e)
        if ((key[e] >> 20) == b1) atomicAdd(&hist[(key[e] >> 10) & 1023u], 1u);
    __syncthreads();
    suffixScanFind(hist, 1024, tid, need, &sBin, &sAbove);
    const unsigned int pfx2 = (b1 << 10) | (unsigned int)sBin;
    need -= sAbove;

    // ---- Round 3: bits [9:0] among prefix-matching, 1024 bins ----
    hist[tid] = 0u;
    __syncthreads();
    #pragma unroll
    for (int e = 0; e < EPT; ++e)
        if ((key[e] >> 10) == pfx2) atomicAdd(&hist[key[e] & 1023u], 1u);
    __syncthreads();
    suffixScanFind(hist, 1024, tid, need, &sBin, &sAbove);
    const unsigned int b3     = (unsigned int)sBin;
    const unsigned int above3 = sAbove;
    const unsigned int T      = (pfx2 << 10) | b3;      // exact k-th key
    const unsigned int eqCnt  = hist[b3] - above3;      // # keys == T
    const unsigned int needEq = need - above3;          // how many equals to keep

    // ---- exact tie handling: keep the needEq SMALLEST column indices ----
    const bool tieAll = (needEq == eqCnt);
    if (tid == 0) eqN = 0u;
    __syncthreads();
    if (!tieAll) {
        #pragma unroll
        for (int e = 0; e < EPT; ++e) {
            if (key[e] == T) {
                const unsigned int p = atomicAdd(&eqN, 1u);
                if (p < 256u) eqIdx[p] = ((e >> 2) * TPB + tid) * 4 + (e & 3);
            }
        }
    }
    __syncthreads();
    const unsigned int eqM = (eqN < 256u) ? eqN : 256u;

    // ---- write pass: selected values (bit-exact), zeros elsewhere ----
    #pragma unroll
    for (int j = 0; j < 8; ++j) {
        float4 o;
        #pragma unroll
        for (int l = 0; l < 4; ++l) {
            const unsigned int k = key[j * 4 + l];
            bool sel;
            if (k != T) {
                sel = (k > T);
            } else if (tieAll) {
                sel = true;
            } else {
                const int col = (j * TPB + tid) * 4 + l;
                unsigned int r = 0;
                for (unsigned int q = 0; q < eqM; ++q)
                    r += (eqIdx[q] < col) ? 1u : 0u;
                sel = (r < needEq);
            }
            const float val =
                __uint_as_float((k & 0x80000000u) ? (k ^ 0x80000000u) : ~k);
            (&o.x)[l] = sel ? val : 0.0f;
        }
        orow[j * TPB + tid] = o;
    }
}

extern "C" void kernel_launch(void* const* d_in, const int* in_sizes, int n_in,
                              void* d_out, int out_size, void* d_ws, size_t ws_size,
                              hipStream_t stream)
{
    (void)n_in; (void)out_size; (void)d_ws; (void)ws_size;
    const float* x = (const float*)d_in[0];
    float* out = (float*)d_out;
    const int rows = in_sizes[0] / COLS;
    topk_scatter_kernel<<<dim3(rows), dim3(TPB), 0, stream>>>(x, out);
}